// Round 1
// baseline (843.551 us; speedup 1.0000x reference)
//
#include <hip/hip_runtime.h>

// TwoLayerSNN forward: B=256, T=1000, D=32, H=200, O=2
// One block per batch element; thread = hidden unit; sequential over T.

constexpr int TB = 256;   // batch
constexpr int TT = 1000;  // timesteps
constexpr int DD = 32;    // input dim
constexpr int HH = 200;   // hidden
constexpr int OO = 2;     // outputs

__global__ __launch_bounds__(256, 1)
void snn_fwd(const float* __restrict__ x,
             const float* __restrict__ w1,
             const float* __restrict__ w2,
             float* __restrict__ out)
{
    const int b   = blockIdx.x;
    const int tid = threadIdx.x;
    const int wid = tid >> 6;
    const bool act = tid < HH;

    float* __restrict__ outp = out;                                   // [TB][OO]
    float* __restrict__ s1o  = out + (size_t)TB * OO;                 // [TB][TT][HH]
    float* __restrict__ m1o  = s1o + (size_t)TB * TT * HH;            // [TB][TT][HH]
    float* __restrict__ s2o  = m1o + (size_t)TB * TT * HH;            // [TB][TT][OO]
    float* __restrict__ m2o  = s2o + (size_t)TB * TT * OO;            // [TB][TT][OO]

    // Decay constants: computed in f64 (like np) then rounded to f32 at use.
    const float A_SYN1 = (float)0.8187307530779818;                     // exp(-1/5)
    const float IN_SC1 = (float)((1.0 - 0.8187307530779818) * 5.0);
    const float A_MEM1 = (float)0.9048374180359595;                     // exp(-1/10)
    const float B_MEM1 = (float)(1.0 - 0.9048374180359595);
    const float TH1    = 0.5f;
    const float A_SYN2 = (float)0.9048374180359595;                     // exp(-1/10)
    const float IN_SC2 = (float)((1.0 - 0.9048374180359595) * 10.0);
    const float A_MEM2 = (float)0.9512294245007140;                     // exp(-1/20)
    const float B_MEM2 = (float)(1.0 - 0.9512294245007140);
    const float TH2    = 1.0f;

    // Per-thread w1 column (32 regs) and w2 row (2 regs), loaded once.
    float w1c[DD];
#pragma unroll
    for (int d = 0; d < DD; ++d)
        w1c[d] = act ? w1[d * HH + tid] : 0.0f;
    const float w2x = act ? w2[tid * OO + 0] : 0.0f;
    const float w2y = act ? w2[tid * OO + 1] : 0.0f;

    __shared__ float2 part[2][4];   // double-buffered per-wave partials

    const float* __restrict__ xb = x + (size_t)b * TT * DD;

    // current x_t in (scalar) regs; prefetch one step ahead
    float xs[DD];
#pragma unroll
    for (int d = 0; d < DD; ++d) xs[d] = xb[d];

    float syn1 = 0.0f, mem1 = 0.0f;
    float syn2x = 0.0f, syn2y = 0.0f, mem2x = 0.0f, mem2y = 0.0f;
    double accx = 0.0, accy = 0.0;

    size_t l1off = (size_t)b * TT * HH + tid;

    for (int t = 0; t < TT; ++t) {
        // prefetch x_{t+1} (clamped at the end; harmless re-read)
        const float* xnp_ = xb + (size_t)((t < TT - 1) ? (t + 1) : t) * DD;
        float xn[DD];
#pragma unroll
        for (int d = 0; d < DD; ++d) xn[d] = xnp_[d];

        // layer-1 GEMV: dot(x_t, w1[:,h]) with 4 accumulators (ILP)
        float a0 = 0.f, a1 = 0.f, a2 = 0.f, a3 = 0.f;
#pragma unroll
        for (int d = 0; d < DD; d += 4) {
            a0 = fmaf(xs[d + 0], w1c[d + 0], a0);
            a1 = fmaf(xs[d + 1], w1c[d + 1], a1);
            a2 = fmaf(xs[d + 2], w1c[d + 2], a2);
            a3 = fmaf(xs[d + 3], w1c[d + 3], a3);
        }
        const float dot = __fadd_rn(__fadd_rn(a0, a1), __fadd_rn(a2, a3));

        // state update — explicit rn ops to match reference's mul/add rounding
        syn1 = __fadd_rn(__fmul_rn(A_SYN1, syn1), __fmul_rn(IN_SC1, dot));
        mem1 = __fadd_rn(__fmul_rn(A_MEM1, mem1), __fmul_rn(B_MEM1, syn1));
        const float s1v = (mem1 - TH1 > 0.0f) ? 1.0f : 0.0f;
        mem1 = __fsub_rn(mem1, __fmul_rn(s1v, TH1));

        if (act) {
            s1o[l1off] = s1v;
            m1o[l1off] = mem1;
        }

        // layer-2 input: wave-level tree reduction of s1*w2 (exact products)
        float cx = s1v * w2x;   // 0 on inactive lanes (w2x==0)
        float cy = s1v * w2y;
#pragma unroll
        for (int off = 32; off >= 1; off >>= 1) {
            cx += __shfl_xor(cx, off, 64);
            cy += __shfl_xor(cy, off, 64);
        }
        if ((tid & 63) == 0) part[t & 1][wid] = make_float2(cx, cy);

        // rotate prefetched x into place (reg renames)
#pragma unroll
        for (int d = 0; d < DD; ++d) xs[d] = xn[d];

        __syncthreads();

        if (tid == 0) {
            const float2 p0 = part[t & 1][0];
            const float2 p1 = part[t & 1][1];
            const float2 p2 = part[t & 1][2];
            const float2 p3 = part[t & 1][3];
            const float dx = __fadd_rn(__fadd_rn(p0.x, p1.x), __fadd_rn(p2.x, p3.x));
            const float dy = __fadd_rn(__fadd_rn(p0.y, p1.y), __fadd_rn(p2.y, p3.y));
            syn2x = __fadd_rn(__fmul_rn(A_SYN2, syn2x), __fmul_rn(IN_SC2, dx));
            syn2y = __fadd_rn(__fmul_rn(A_SYN2, syn2y), __fmul_rn(IN_SC2, dy));
            mem2x = __fadd_rn(__fmul_rn(A_MEM2, mem2x), __fmul_rn(B_MEM2, syn2x));
            mem2y = __fadd_rn(__fmul_rn(A_MEM2, mem2y), __fmul_rn(B_MEM2, syn2y));
            const float s2x = (mem2x - TH2 > 0.0f) ? 1.0f : 0.0f;
            const float s2y = (mem2y - TH2 > 0.0f) ? 1.0f : 0.0f;
            mem2x = __fsub_rn(mem2x, __fmul_rn(s2x, TH2));
            mem2y = __fsub_rn(mem2y, __fmul_rn(s2y, TH2));
            const size_t l2 = ((size_t)b * TT + t) * OO;
            s2o[l2 + 0] = s2x;
            s2o[l2 + 1] = s2y;
            m2o[l2 + 0] = mem2x;
            m2o[l2 + 1] = mem2y;
            if (t > 0) { accx += (double)mem2x; accy += (double)mem2y; }
        }

        l1off += HH;
    }

    if (tid == 0) {
        outp[b * OO + 0] = (float)accx / 1000.0f;
        outp[b * OO + 1] = (float)accy / 1000.0f;
    }
}

extern "C" void kernel_launch(void* const* d_in, const int* in_sizes, int n_in,
                              void* d_out, int out_size, void* d_ws, size_t ws_size,
                              hipStream_t stream) {
    const float* x  = (const float*)d_in[0];   // [256,1000,32]
    const float* w1 = (const float*)d_in[1];   // [32,200]
    const float* w2 = (const float*)d_in[2];   // [200,2]
    float* out = (float*)d_out;                // 103,424,512 f32, concatenated outputs

    dim3 grid(TB), block(256);
    hipLaunchKernelGGL(snn_fwd, grid, block, 0, stream, x, w1, w2, out);
}

// Round 2
// 487.250 us; speedup vs baseline: 1.7312x; 1.7312x over previous
//
#include <hip/hip_runtime.h>

// TwoLayerSNN forward: B=256, T=1000, D=32, H=200, O=2
// One block/batch, 256 threads (4 waves), sequential over T.
// - x staged through double-buffered LDS chunks (async split staging)
// - layer-1: thread h computes dot(x_t, w1[:,h]) from registers
// - layer-2 drive: DPP wave reduction -> lane63 writes per-wave partial to LDS
// - layer-2 recurrence replicated on all threads, lagged one step
// - raw s_barrier + lgkmcnt(0) (no per-step vmcnt drain)

constexpr int TB = 256;
constexpr int TT = 1000;
constexpr int DD = 32;
constexpr int HH = 200;
constexpr int OO = 2;
constexpr int CH = 64;                    // timesteps per x chunk
constexpr int NCH = (TT + CH - 1) / CH;   // 16

__device__ __forceinline__ void wave_sum2(float& a, float& b) {
    // wave64 sum; result valid in lane 63 of each wave.
#define DPP_STEP(CTRL)                                                          \
    {                                                                           \
        int ta = __builtin_amdgcn_update_dpp(0, __float_as_int(a), CTRL, 0xf, 0xf, true); \
        int tb = __builtin_amdgcn_update_dpp(0, __float_as_int(b), CTRL, 0xf, 0xf, true); \
        a += __int_as_float(ta);                                                \
        b += __int_as_float(tb);                                                \
    }
    DPP_STEP(0x111)  // row_shr:1
    DPP_STEP(0x112)  // row_shr:2
    DPP_STEP(0x114)  // row_shr:4
    DPP_STEP(0x118)  // row_shr:8
    DPP_STEP(0x142)  // row_bcast:15
    DPP_STEP(0x143)  // row_bcast:31
#undef DPP_STEP
}

__device__ __forceinline__ void block_sync() {
    asm volatile("s_waitcnt lgkmcnt(0)" ::: "memory");
    __builtin_amdgcn_s_barrier();
    asm volatile("" ::: "memory");
}

__global__ __launch_bounds__(256, 1)
void snn_fwd(const float* __restrict__ x,
             const float* __restrict__ w1,
             const float* __restrict__ w2,
             float* __restrict__ out)
{
    const int b    = blockIdx.x;
    const int tid  = threadIdx.x;
    const int lane = tid & 63;
    const bool act = tid < HH;

    float* __restrict__ outp = out;                        // [TB][OO]
    float* __restrict__ s1o  = out + (size_t)TB * OO;      // [TB][TT][HH]
    float* __restrict__ m1o  = s1o + (size_t)TB * TT * HH; // [TB][TT][HH]
    float* __restrict__ s2o  = m1o + (size_t)TB * TT * HH; // [TB][TT][OO]
    float* __restrict__ m2o  = s2o + (size_t)TB * TT * OO; // [TB][TT][OO]

    const float A_SYN1 = (float)0.8187307530779818;
    const float IN_SC1 = (float)((1.0 - 0.8187307530779818) * 5.0);
    const float A_MEM1 = (float)0.9048374180359595;
    const float B_MEM1 = (float)(1.0 - 0.9048374180359595);
    const float TH1    = 0.5f;
    const float A_SYN2 = (float)0.9048374180359595;
    const float IN_SC2 = (float)((1.0 - 0.9048374180359595) * 10.0);
    const float A_MEM2 = (float)0.9512294245007140;
    const float B_MEM2 = (float)(1.0 - 0.9512294245007140);
    const float TH2    = 1.0f;

    __shared__ float4 xls[2][CH * DD / 4];  // 2 x 8 KB
    __shared__ float4 partv[2][2];          // per-wave (cx,cy) partials, dbuf

    const float* __restrict__ xb = x + (size_t)b * TT * DD;

    // per-thread weights in registers
    float w1c[DD];
#pragma unroll
    for (int d = 0; d < DD; ++d) w1c[d] = act ? w1[d * HH + tid] : 0.0f;
    const float w2x = act ? w2[tid * OO + 0] : 0.0f;
    const float w2y = act ? w2[tid * OO + 1] : 0.0f;

    // stage chunk 0 (full 8 KB): 2 float4 per thread
    {
        const float4* g = (const float4*)xb;
        float4 r0 = g[2 * tid];
        float4 r1 = g[2 * tid + 1];
        xls[0][2 * tid]     = r0;
        xls[0][2 * tid + 1] = r1;
    }
    block_sync();

    float syn1 = 0.0f, mem1 = 0.0f;
    float syn2x = 0.0f, syn2y = 0.0f, mem2x = 0.0f, mem2y = 0.0f;
    double accx = 0.0, accy = 0.0;
    float4 pr0 = make_float4(0.f, 0.f, 0.f, 0.f);
    float4 pr1 = make_float4(0.f, 0.f, 0.f, 0.f);

    size_t l1off = (size_t)b * TT * HH + tid;

    auto layer2 = [&](int s) {
        const int pb = s & 1;
        const float4 q0 = partv[pb][0];
        const float4 q1 = partv[pb][1];
        const float dx = __fadd_rn(__fadd_rn(q0.x, q0.z), __fadd_rn(q1.x, q1.z));
        const float dy = __fadd_rn(__fadd_rn(q0.y, q0.w), __fadd_rn(q1.y, q1.w));
        syn2x = __fadd_rn(__fmul_rn(A_SYN2, syn2x), __fmul_rn(IN_SC2, dx));
        syn2y = __fadd_rn(__fmul_rn(A_SYN2, syn2y), __fmul_rn(IN_SC2, dy));
        mem2x = __fadd_rn(__fmul_rn(A_MEM2, mem2x), __fmul_rn(B_MEM2, syn2x));
        mem2y = __fadd_rn(__fmul_rn(A_MEM2, mem2y), __fmul_rn(B_MEM2, syn2y));
        const float s2x = (mem2x - TH2 > 0.0f) ? 1.0f : 0.0f;
        const float s2y = (mem2y - TH2 > 0.0f) ? 1.0f : 0.0f;
        mem2x = __fsub_rn(mem2x, __fmul_rn(s2x, TH2));
        mem2y = __fsub_rn(mem2y, __fmul_rn(s2y, TH2));
        if (tid == 0) {
            const size_t l2 = ((size_t)b * TT + s) * OO;
            *(float2*)&s2o[l2] = make_float2(s2x, s2y);
            *(float2*)&m2o[l2] = make_float2(mem2x, mem2y);
        }
        if (s > 0) { accx += (double)mem2x; accy += (double)mem2y; }
    };

    for (int t = 0; t < TT; ++t) {
        const int cpos = t & (CH - 1);
        const int c    = t >> 6;
        const int buf  = c & 1;

        // issue next-chunk global loads at chunk start (latency hidden 62 steps)
        if (cpos == 0 && c + 1 < NCH) {
            const int nst  = (CH < TT - (c + 1) * CH) ? CH : (TT - (c + 1) * CH);
            const int nfl4 = nst * DD / 4;
            const float4* g = (const float4*)(xb + (size_t)(c + 1) * CH * DD);
            if (2 * tid     < nfl4) pr0 = g[2 * tid];
            if (2 * tid + 1 < nfl4) pr1 = g[2 * tid + 1];
        }
        // commit staged regs to the other LDS buffer near chunk end
        if (cpos == CH - 2 && c + 1 < NCH) {
            const int nst  = (CH < TT - (c + 1) * CH) ? CH : (TT - (c + 1) * CH);
            const int nfl4 = nst * DD / 4;
            if (2 * tid     < nfl4) xls[buf ^ 1][2 * tid]     = pr0;
            if (2 * tid + 1 < nfl4) xls[buf ^ 1][2 * tid + 1] = pr1;
        }

        // x_t: 8 broadcast ds_read_b128 (issued early)
        const float4* xp = &xls[buf][cpos * (DD / 4)];
        const float4 X0 = xp[0], X1 = xp[1], X2 = xp[2], X3 = xp[3];
        const float4 X4 = xp[4], X5 = xp[5], X6 = xp[6], X7 = xp[7];

        // layer-2 for previous step — independent of x_t, overlaps LDS latency
        if (t > 0) layer2(t - 1);

        // layer-1 dot: same accumulator structure/rounding as validated round 1
        float a0 = 0.f, a1 = 0.f, a2 = 0.f, a3 = 0.f;
        a0 = fmaf(X0.x, w1c[0],  a0); a1 = fmaf(X0.y, w1c[1],  a1);
        a2 = fmaf(X0.z, w1c[2],  a2); a3 = fmaf(X0.w, w1c[3],  a3);
        a0 = fmaf(X1.x, w1c[4],  a0); a1 = fmaf(X1.y, w1c[5],  a1);
        a2 = fmaf(X1.z, w1c[6],  a2); a3 = fmaf(X1.w, w1c[7],  a3);
        a0 = fmaf(X2.x, w1c[8],  a0); a1 = fmaf(X2.y, w1c[9],  a1);
        a2 = fmaf(X2.z, w1c[10], a2); a3 = fmaf(X2.w, w1c[11], a3);
        a0 = fmaf(X3.x, w1c[12], a0); a1 = fmaf(X3.y, w1c[13], a1);
        a2 = fmaf(X3.z, w1c[14], a2); a3 = fmaf(X3.w, w1c[15], a3);
        a0 = fmaf(X4.x, w1c[16], a0); a1 = fmaf(X4.y, w1c[17], a1);
        a2 = fmaf(X4.z, w1c[18], a2); a3 = fmaf(X4.w, w1c[19], a3);
        a0 = fmaf(X5.x, w1c[20], a0); a1 = fmaf(X5.y, w1c[21], a1);
        a2 = fmaf(X5.z, w1c[22], a2); a3 = fmaf(X5.w, w1c[23], a3);
        a0 = fmaf(X6.x, w1c[24], a0); a1 = fmaf(X6.y, w1c[25], a1);
        a2 = fmaf(X6.z, w1c[26], a2); a3 = fmaf(X6.w, w1c[27], a3);
        a0 = fmaf(X7.x, w1c[28], a0); a1 = fmaf(X7.y, w1c[29], a1);
        a2 = fmaf(X7.z, w1c[30], a2); a3 = fmaf(X7.w, w1c[31], a3);
        const float dot = __fadd_rn(__fadd_rn(a0, a1), __fadd_rn(a2, a3));

        syn1 = __fadd_rn(__fmul_rn(A_SYN1, syn1), __fmul_rn(IN_SC1, dot));
        mem1 = __fadd_rn(__fmul_rn(A_MEM1, mem1), __fmul_rn(B_MEM1, syn1));
        const float s1v = (mem1 - TH1 > 0.0f) ? 1.0f : 0.0f;
        mem1 = __fsub_rn(mem1, __fmul_rn(s1v, TH1));

        if (act) {
            s1o[l1off] = s1v;
            m1o[l1off] = mem1;
        }

        // layer-2 drive partials: DPP wave reduction (valid in lane 63)
        float cx = s1v * w2x;
        float cy = s1v * w2y;
        wave_sum2(cx, cy);
        if (lane == 63) {
            float2* pw = (float2*)&partv[t & 1][0];
            pw[tid >> 6] = make_float2(cx, cy);
        }

        l1off += HH;
        block_sync();
    }

    // epilogue: layer-2 for the final step
    layer2(TT - 1);

    if (tid == 0) {
        outp[b * OO + 0] = (float)accx / 1000.0f;
        outp[b * OO + 1] = (float)accy / 1000.0f;
    }
}

extern "C" void kernel_launch(void* const* d_in, const int* in_sizes, int n_in,
                              void* d_out, int out_size, void* d_ws, size_t ws_size,
                              hipStream_t stream) {
    const float* x  = (const float*)d_in[0];   // [256,1000,32]
    const float* w1 = (const float*)d_in[1];   // [32,200]
    const float* w2 = (const float*)d_in[2];   // [200,2]
    float* out = (float*)d_out;

    dim3 grid(TB), block(256);
    hipLaunchKernelGGL(snn_fwd, grid, block, 0, stream, x, w1, w2, out);
}

// Round 6
// 385.210 us; speedup vs baseline: 2.1898x; 1.2649x over previous
//
#include <hip/hip_runtime.h>

// TwoLayerSNN forward: B=256, T=1000, D=32, H=200, O=2
// One block/batch, 256 threads (4 waves). Round 6: per-step inner body is
// TEXTUALLY round 2's (passing): one dot per step, per-step s1/m1 stores,
// per-step sequential DPP wave reduction, per-step lane63 partv write.
// Changes vs round 2: one __syncthreads per 8 steps (not per step); layer-2
// lagged by one sub-chunk (parity LDS buffer); x-chunk prefetch regs HOISTED
// out of the loop (round-5 bug: they were loop-local and died between the
// load iteration and the commit iteration).

constexpr int TB = 256;
constexpr int TT = 1000;
constexpr int DD = 32;
constexpr int HH = 200;
constexpr int OO = 2;
constexpr int CH = 64;                    // timesteps per x staging chunk (8 KB)
constexpr int NCH = (TT + CH - 1) / CH;   // 16
constexpr int SC = 8;                     // timesteps per barrier interval
constexpr int NSC = TT / SC;              // 125

__device__ __forceinline__ void wave_sum2(float& a, float& b) {
    // wave64 sum; result valid in lane 63 of each wave. (verified round 2)
#define DPP_STEP(CTRL)                                                          \
    {                                                                           \
        int ta = __builtin_amdgcn_update_dpp(0, __float_as_int(a), CTRL, 0xf, 0xf, true); \
        int tb = __builtin_amdgcn_update_dpp(0, __float_as_int(b), CTRL, 0xf, 0xf, true); \
        a += __int_as_float(ta);                                                \
        b += __int_as_float(tb);                                                \
    }
    DPP_STEP(0x111)  // row_shr:1
    DPP_STEP(0x112)  // row_shr:2
    DPP_STEP(0x114)  // row_shr:4
    DPP_STEP(0x118)  // row_shr:8
    DPP_STEP(0x142)  // row_bcast:15
    DPP_STEP(0x143)  // row_bcast:31
#undef DPP_STEP
}

__global__ __launch_bounds__(256, 1)
void snn_fwd(const float* __restrict__ x,
             const float* __restrict__ w1,
             const float* __restrict__ w2,
             float* __restrict__ out)
{
    const int b    = blockIdx.x;
    const int tid  = threadIdx.x;
    const int lane = tid & 63;
    const int wid  = tid >> 6;
    const bool act = tid < HH;

    float* __restrict__ outp = out;                        // [TB][OO]
    float* __restrict__ s1o  = out + (size_t)TB * OO;      // [TB][TT][HH]
    float* __restrict__ m1o  = s1o + (size_t)TB * TT * HH; // [TB][TT][HH]
    float* __restrict__ s2o  = m1o + (size_t)TB * TT * HH; // [TB][TT][OO]
    float* __restrict__ m2o  = s2o + (size_t)TB * TT * OO; // [TB][TT][OO]

    const float A_SYN1 = (float)0.8187307530779818;
    const float IN_SC1 = (float)((1.0 - 0.8187307530779818) * 5.0);
    const float A_MEM1 = (float)0.9048374180359595;
    const float B_MEM1 = (float)(1.0 - 0.9048374180359595);
    const float TH1    = 0.5f;
    const float A_SYN2 = (float)0.9048374180359595;
    const float IN_SC2 = (float)((1.0 - 0.9048374180359595) * 10.0);
    const float A_MEM2 = (float)0.9512294245007140;
    const float B_MEM2 = (float)(1.0 - 0.9512294245007140);
    const float TH2    = 1.0f;

    __shared__ float4 xls[2][CH * DD / 4];           // 2 x 8 KB
    __shared__ __align__(16) float2 partv[2][SC][4]; // parity x step x wave

    const float* __restrict__ xb = x + (size_t)b * TT * DD;

    float w1c[DD];
#pragma unroll
    for (int d = 0; d < DD; ++d) w1c[d] = act ? w1[d * HH + tid] : 0.0f;
    const float w2x = act ? w2[tid * OO + 0] : 0.0f;
    const float w2y = act ? w2[tid * OO + 1] : 0.0f;

    // stage chunk 0 (full 8 KB): 2 float4 per thread
    {
        const float4* g = (const float4*)xb;
        xls[0][2 * tid]     = g[2 * tid];
        xls[0][2 * tid + 1] = g[2 * tid + 1];
    }
    __syncthreads();

    float syn1 = 0.0f, mem1 = 0.0f;
    float syn2x = 0.0f, syn2y = 0.0f, mem2x = 0.0f, mem2y = 0.0f;
    double accx = 0.0, accy = 0.0;

    // PERSISTENT staging state (round-5 bug fix: these must outlive the
    // iteration that loads them, since the commit is 7 iterations later)
    float4 pr0 = make_float4(0.f, 0.f, 0.f, 0.f);
    float4 pr1 = make_float4(0.f, 0.f, 0.f, 0.f);
    int nfl4 = 0;

    float* __restrict__ s1p = s1o + (size_t)b * TT * HH + tid;
    float* __restrict__ m1p = m1o + (size_t)b * TT * HH + tid;
    float2* __restrict__ s2p = (float2*)(s2o + (size_t)b * TT * OO);
    float2* __restrict__ m2p = (float2*)(m2o + (size_t)b * TT * OO);

    // layer-2 for sub-chunk j (replicated on all threads; tid0 stores)
    auto layer2_chunk = [&](int j) {
#pragma unroll
        for (int s = 0; s < SC; ++s) {
            const float4* pv = (const float4*)&partv[j & 1][s][0];
            const float4 q0 = pv[0];
            const float4 q1 = pv[1];
            const float dx = __fadd_rn(__fadd_rn(q0.x, q0.z), __fadd_rn(q1.x, q1.z));
            const float dy = __fadd_rn(__fadd_rn(q0.y, q0.w), __fadd_rn(q1.y, q1.w));
            syn2x = __fadd_rn(__fmul_rn(A_SYN2, syn2x), __fmul_rn(IN_SC2, dx));
            syn2y = __fadd_rn(__fmul_rn(A_SYN2, syn2y), __fmul_rn(IN_SC2, dy));
            mem2x = __fadd_rn(__fmul_rn(A_MEM2, mem2x), __fmul_rn(B_MEM2, syn2x));
            mem2y = __fadd_rn(__fmul_rn(A_MEM2, mem2y), __fmul_rn(B_MEM2, syn2y));
            const float s2x = (mem2x - TH2 > 0.0f) ? 1.0f : 0.0f;
            const float s2y = (mem2y - TH2 > 0.0f) ? 1.0f : 0.0f;
            mem2x = __fsub_rn(mem2x, __fmul_rn(s2x, TH2));
            mem2y = __fsub_rn(mem2y, __fmul_rn(s2y, TH2));
            const int t = j * SC + s;
            if (tid == 0) {
                s2p[t] = make_float2(s2x, s2y);
                m2p[t] = make_float2(mem2x, mem2y);
            }
            if (t > 0) { accx += (double)mem2x; accy += (double)mem2y; }
        }
    };

    for (int sc = 0; sc < NSC; ++sc) {
        const int t0   = sc * SC;
        const int c    = t0 >> 6;
        const int buf  = c & 1;
        const int cpos = t0 & 63;

        // staging: first sub-chunk of chunk c loads chunk c+1 into persistent
        // registers; last sub-chunk of chunk c commits them to xls[buf^1].
        if (cpos == 0 && c + 1 < NCH) {
            const int nst = (CH < TT - (c + 1) * CH) ? CH : (TT - (c + 1) * CH);
            nfl4 = nst * DD / 4;
            const float4* g = (const float4*)(xb + (size_t)(c + 1) * CH * DD);
            if (2 * tid     < nfl4) pr0 = g[2 * tid];
            if (2 * tid + 1 < nfl4) pr1 = g[2 * tid + 1];
        }

        const float4* xp = &xls[buf][cpos * (DD / 4)];

        // layer-2 for previous sub-chunk — overlaps with the dots below
        if (sc > 0) layer2_chunk(sc - 1);

        // per-step body: textually round 2's (passing) code
#pragma unroll
        for (int s = 0; s < SC; ++s) {
            const float4 X0 = xp[s * 8 + 0], X1 = xp[s * 8 + 1];
            const float4 X2 = xp[s * 8 + 2], X3 = xp[s * 8 + 3];
            const float4 X4 = xp[s * 8 + 4], X5 = xp[s * 8 + 5];
            const float4 X6 = xp[s * 8 + 6], X7 = xp[s * 8 + 7];

            float a0 = 0.f, a1 = 0.f, a2 = 0.f, a3 = 0.f;
            a0 = fmaf(X0.x, w1c[0],  a0); a1 = fmaf(X0.y, w1c[1],  a1);
            a2 = fmaf(X0.z, w1c[2],  a2); a3 = fmaf(X0.w, w1c[3],  a3);
            a0 = fmaf(X1.x, w1c[4],  a0); a1 = fmaf(X1.y, w1c[5],  a1);
            a2 = fmaf(X1.z, w1c[6],  a2); a3 = fmaf(X1.w, w1c[7],  a3);
            a0 = fmaf(X2.x, w1c[8],  a0); a1 = fmaf(X2.y, w1c[9],  a1);
            a2 = fmaf(X2.z, w1c[10], a2); a3 = fmaf(X2.w, w1c[11], a3);
            a0 = fmaf(X3.x, w1c[12], a0); a1 = fmaf(X3.y, w1c[13], a1);
            a2 = fmaf(X3.z, w1c[14], a2); a3 = fmaf(X3.w, w1c[15], a3);
            a0 = fmaf(X4.x, w1c[16], a0); a1 = fmaf(X4.y, w1c[17], a1);
            a2 = fmaf(X4.z, w1c[18], a2); a3 = fmaf(X4.w, w1c[19], a3);
            a0 = fmaf(X5.x, w1c[20], a0); a1 = fmaf(X5.y, w1c[21], a1);
            a2 = fmaf(X5.z, w1c[22], a2); a3 = fmaf(X5.w, w1c[23], a3);
            a0 = fmaf(X6.x, w1c[24], a0); a1 = fmaf(X6.y, w1c[25], a1);
            a2 = fmaf(X6.z, w1c[26], a2); a3 = fmaf(X6.w, w1c[27], a3);
            a0 = fmaf(X7.x, w1c[28], a0); a1 = fmaf(X7.y, w1c[29], a1);
            a2 = fmaf(X7.z, w1c[30], a2); a3 = fmaf(X7.w, w1c[31], a3);
            const float dot = __fadd_rn(__fadd_rn(a0, a1), __fadd_rn(a2, a3));

            syn1 = __fadd_rn(__fmul_rn(A_SYN1, syn1), __fmul_rn(IN_SC1, dot));
            mem1 = __fadd_rn(__fmul_rn(A_MEM1, mem1), __fmul_rn(B_MEM1, syn1));
            const float s1v = (mem1 - TH1 > 0.0f) ? 1.0f : 0.0f;
            mem1 = __fsub_rn(mem1, __fmul_rn(s1v, TH1));

            if (act) {
                s1p[(size_t)(t0 + s) * HH] = s1v;
                m1p[(size_t)(t0 + s) * HH] = mem1;
            }

            float cx = s1v * w2x;
            float cy = s1v * w2y;
            wave_sum2(cx, cy);   // sequential per-step DPP tree (round-2 order)
            if (lane == 63)
                partv[sc & 1][s][wid] = make_float2(cx, cy);
        }

        // commit next chunk's x to the other LDS buffer (last sub-chunk of c)
        if (cpos == 56 && c + 1 < NCH) {
            if (2 * tid     < nfl4) xls[buf ^ 1][2 * tid]     = pr0;
            if (2 * tid + 1 < nfl4) xls[buf ^ 1][2 * tid + 1] = pr1;
        }

        __syncthreads();
    }

    // epilogue: layer-2 for the final sub-chunk
    layer2_chunk(NSC - 1);

    if (tid == 0) {
        outp[b * OO + 0] = (float)accx / 1000.0f;
        outp[b * OO + 1] = (float)accy / 1000.0f;
    }
}

extern "C" void kernel_launch(void* const* d_in, const int* in_sizes, int n_in,
                              void* d_out, int out_size, void* d_ws, size_t ws_size,
                              hipStream_t stream) {
    const float* x  = (const float*)d_in[0];   // [256,1000,32]
    const float* w1 = (const float*)d_in[1];   // [32,200]
    const float* w2 = (const float*)d_in[2];   // [200,2]
    float* out = (float*)d_out;

    dim3 grid(TB), block(256);
    hipLaunchKernelGGL(snn_fwd, grid, block, 0, stream, x, w1, w2, out);
}

// Round 7
// 362.023 us; speedup vs baseline: 2.3301x; 1.0640x over previous
//
#include <hip/hip_runtime.h>

// TwoLayerSNN forward: B=256, T=1000, D=32, H=200, O=2
// One block/batch, 256 threads (4 waves). Round 7 = round 6 (passing) with
// latency hoisting ONLY: (a) partv for the lagged layer-2 is burst-read into
// registers at sub-chunk top (prev parity, barrier-separated), (b) step-0 x
// block read at top, (c) 1-step-ahead x prefetch inside the step loop via
// fully-unrolled register rotation. All arithmetic / stores / DPP / barrier
// placement textually identical to round 6.

constexpr int TB = 256;
constexpr int TT = 1000;
constexpr int DD = 32;
constexpr int HH = 200;
constexpr int OO = 2;
constexpr int CH = 64;                    // timesteps per x staging chunk (8 KB)
constexpr int NCH = (TT + CH - 1) / CH;   // 16
constexpr int SC = 8;                     // timesteps per barrier interval
constexpr int NSC = TT / SC;              // 125

__device__ __forceinline__ void wave_sum2(float& a, float& b) {
    // wave64 sum; result valid in lane 63 of each wave. (verified rounds 2/6)
#define DPP_STEP(CTRL)                                                          \
    {                                                                           \
        int ta = __builtin_amdgcn_update_dpp(0, __float_as_int(a), CTRL, 0xf, 0xf, true); \
        int tb = __builtin_amdgcn_update_dpp(0, __float_as_int(b), CTRL, 0xf, 0xf, true); \
        a += __int_as_float(ta);                                                \
        b += __int_as_float(tb);                                                \
    }
    DPP_STEP(0x111)  // row_shr:1
    DPP_STEP(0x112)  // row_shr:2
    DPP_STEP(0x114)  // row_shr:4
    DPP_STEP(0x118)  // row_shr:8
    DPP_STEP(0x142)  // row_bcast:15
    DPP_STEP(0x143)  // row_bcast:31
#undef DPP_STEP
}

__global__ __launch_bounds__(256, 1)
void snn_fwd(const float* __restrict__ x,
             const float* __restrict__ w1,
             const float* __restrict__ w2,
             float* __restrict__ out)
{
    const int b    = blockIdx.x;
    const int tid  = threadIdx.x;
    const int lane = tid & 63;
    const int wid  = tid >> 6;
    const bool act = tid < HH;

    float* __restrict__ outp = out;                        // [TB][OO]
    float* __restrict__ s1o  = out + (size_t)TB * OO;      // [TB][TT][HH]
    float* __restrict__ m1o  = s1o + (size_t)TB * TT * HH; // [TB][TT][HH]
    float* __restrict__ s2o  = m1o + (size_t)TB * TT * HH; // [TB][TT][OO]
    float* __restrict__ m2o  = s2o + (size_t)TB * TT * OO; // [TB][TT][OO]

    const float A_SYN1 = (float)0.8187307530779818;
    const float IN_SC1 = (float)((1.0 - 0.8187307530779818) * 5.0);
    const float A_MEM1 = (float)0.9048374180359595;
    const float B_MEM1 = (float)(1.0 - 0.9048374180359595);
    const float TH1    = 0.5f;
    const float A_SYN2 = (float)0.9048374180359595;
    const float IN_SC2 = (float)((1.0 - 0.9048374180359595) * 10.0);
    const float A_MEM2 = (float)0.9512294245007140;
    const float B_MEM2 = (float)(1.0 - 0.9512294245007140);
    const float TH2    = 1.0f;

    __shared__ float4 xls[2][CH * DD / 4];           // 2 x 8 KB
    __shared__ __align__(16) float2 partv[2][SC][4]; // parity x step x wave

    const float* __restrict__ xb = x + (size_t)b * TT * DD;

    float w1c[DD];
#pragma unroll
    for (int d = 0; d < DD; ++d) w1c[d] = act ? w1[d * HH + tid] : 0.0f;
    const float w2x = act ? w2[tid * OO + 0] : 0.0f;
    const float w2y = act ? w2[tid * OO + 1] : 0.0f;

    // stage chunk 0 (full 8 KB): 2 float4 per thread
    {
        const float4* g = (const float4*)xb;
        xls[0][2 * tid]     = g[2 * tid];
        xls[0][2 * tid + 1] = g[2 * tid + 1];
    }
    __syncthreads();

    float syn1 = 0.0f, mem1 = 0.0f;
    float syn2x = 0.0f, syn2y = 0.0f, mem2x = 0.0f, mem2y = 0.0f;
    double accx = 0.0, accy = 0.0;

    // PERSISTENT staging state (must outlive the loading iteration)
    float4 pr0 = make_float4(0.f, 0.f, 0.f, 0.f);
    float4 pr1 = make_float4(0.f, 0.f, 0.f, 0.f);
    int nfl4 = 0;

    float* __restrict__ s1p = s1o + (size_t)b * TT * HH + tid;
    float* __restrict__ m1p = m1o + (size_t)b * TT * HH + tid;
    float2* __restrict__ s2p = (float2*)(s2o + (size_t)b * TT * OO);
    float2* __restrict__ m2p = (float2*)(m2o + (size_t)b * TT * OO);

    // epilogue-only layer-2 (reads partv from LDS; identical chain)
    auto layer2_chunk = [&](int j) {
#pragma unroll
        for (int s = 0; s < SC; ++s) {
            const float4* pv = (const float4*)&partv[j & 1][s][0];
            const float4 q0 = pv[0];
            const float4 q1 = pv[1];
            const float dx = __fadd_rn(__fadd_rn(q0.x, q0.z), __fadd_rn(q1.x, q1.z));
            const float dy = __fadd_rn(__fadd_rn(q0.y, q0.w), __fadd_rn(q1.y, q1.w));
            syn2x = __fadd_rn(__fmul_rn(A_SYN2, syn2x), __fmul_rn(IN_SC2, dx));
            syn2y = __fadd_rn(__fmul_rn(A_SYN2, syn2y), __fmul_rn(IN_SC2, dy));
            mem2x = __fadd_rn(__fmul_rn(A_MEM2, mem2x), __fmul_rn(B_MEM2, syn2x));
            mem2y = __fadd_rn(__fmul_rn(A_MEM2, mem2y), __fmul_rn(B_MEM2, syn2y));
            const float s2x = (mem2x - TH2 > 0.0f) ? 1.0f : 0.0f;
            const float s2y = (mem2y - TH2 > 0.0f) ? 1.0f : 0.0f;
            mem2x = __fsub_rn(mem2x, __fmul_rn(s2x, TH2));
            mem2y = __fsub_rn(mem2y, __fmul_rn(s2y, TH2));
            const int t = j * SC + s;
            if (tid == 0) {
                s2p[t] = make_float2(s2x, s2y);
                m2p[t] = make_float2(mem2x, mem2y);
            }
            if (t > 0) { accx += (double)mem2x; accy += (double)mem2y; }
        }
    };

    for (int sc = 0; sc < NSC; ++sc) {
        const int t0   = sc * SC;
        const int c    = t0 >> 6;
        const int buf  = c & 1;
        const int cpos = t0 & 63;

        // ---- top-of-subchunk load burst ----
        // partv of the PREVIOUS parity (written before the last barrier)
        float4 P[16];
        {
            const float4* pvall = (const float4*)&partv[(sc + 1) & 1][0][0];
#pragma unroll
            for (int i = 0; i < 16; ++i) P[i] = pvall[i];
        }
        // step-0 x block
        const float4* xp = &xls[buf][cpos * (DD / 4)];
        float4 Xc[8];
#pragma unroll
        for (int k = 0; k < 8; ++k) Xc[k] = xp[k];

        // staging: first sub-chunk of chunk c loads chunk c+1 (persistent regs)
        if (cpos == 0 && c + 1 < NCH) {
            const int nst = (CH < TT - (c + 1) * CH) ? CH : (TT - (c + 1) * CH);
            nfl4 = nst * DD / 4;
            const float4* g = (const float4*)(xb + (size_t)(c + 1) * CH * DD);
            if (2 * tid     < nfl4) pr0 = g[2 * tid];
            if (2 * tid + 1 < nfl4) pr1 = g[2 * tid + 1];
        }

        // ---- layer-2 for previous sub-chunk, from registers ----
        if (sc > 0) {
#pragma unroll
            for (int s = 0; s < SC; ++s) {
                const float4 q0 = P[2 * s];
                const float4 q1 = P[2 * s + 1];
                const float dx = __fadd_rn(__fadd_rn(q0.x, q0.z), __fadd_rn(q1.x, q1.z));
                const float dy = __fadd_rn(__fadd_rn(q0.y, q0.w), __fadd_rn(q1.y, q1.w));
                syn2x = __fadd_rn(__fmul_rn(A_SYN2, syn2x), __fmul_rn(IN_SC2, dx));
                syn2y = __fadd_rn(__fmul_rn(A_SYN2, syn2y), __fmul_rn(IN_SC2, dy));
                mem2x = __fadd_rn(__fmul_rn(A_MEM2, mem2x), __fmul_rn(B_MEM2, syn2x));
                mem2y = __fadd_rn(__fmul_rn(A_MEM2, mem2y), __fmul_rn(B_MEM2, syn2y));
                const float s2x = (mem2x - TH2 > 0.0f) ? 1.0f : 0.0f;
                const float s2y = (mem2y - TH2 > 0.0f) ? 1.0f : 0.0f;
                mem2x = __fsub_rn(mem2x, __fmul_rn(s2x, TH2));
                mem2y = __fsub_rn(mem2y, __fmul_rn(s2y, TH2));
                const int t = (sc - 1) * SC + s;
                if (tid == 0) {
                    s2p[t] = make_float2(s2x, s2y);
                    m2p[t] = make_float2(mem2x, mem2y);
                }
                if (t > 0) { accx += (double)mem2x; accy += (double)mem2y; }
            }
        }

        // ---- 8 steps; per-step body textually round 6's; x via rotation ----
#pragma unroll
        for (int s = 0; s < SC; ++s) {
            // prefetch next step's x block (latency hides under this step)
            float4 Xn[8];
            if (s < SC - 1) {
#pragma unroll
                for (int k = 0; k < 8; ++k) Xn[k] = xp[(s + 1) * 8 + k];
            }

            const float4 X0 = Xc[0], X1 = Xc[1], X2 = Xc[2], X3 = Xc[3];
            const float4 X4 = Xc[4], X5 = Xc[5], X6 = Xc[6], X7 = Xc[7];

            float a0 = 0.f, a1 = 0.f, a2 = 0.f, a3 = 0.f;
            a0 = fmaf(X0.x, w1c[0],  a0); a1 = fmaf(X0.y, w1c[1],  a1);
            a2 = fmaf(X0.z, w1c[2],  a2); a3 = fmaf(X0.w, w1c[3],  a3);
            a0 = fmaf(X1.x, w1c[4],  a0); a1 = fmaf(X1.y, w1c[5],  a1);
            a2 = fmaf(X1.z, w1c[6],  a2); a3 = fmaf(X1.w, w1c[7],  a3);
            a0 = fmaf(X2.x, w1c[8],  a0); a1 = fmaf(X2.y, w1c[9],  a1);
            a2 = fmaf(X2.z, w1c[10], a2); a3 = fmaf(X2.w, w1c[11], a3);
            a0 = fmaf(X3.x, w1c[12], a0); a1 = fmaf(X3.y, w1c[13], a1);
            a2 = fmaf(X3.z, w1c[14], a2); a3 = fmaf(X3.w, w1c[15], a3);
            a0 = fmaf(X4.x, w1c[16], a0); a1 = fmaf(X4.y, w1c[17], a1);
            a2 = fmaf(X4.z, w1c[18], a2); a3 = fmaf(X4.w, w1c[19], a3);
            a0 = fmaf(X5.x, w1c[20], a0); a1 = fmaf(X5.y, w1c[21], a1);
            a2 = fmaf(X5.z, w1c[22], a2); a3 = fmaf(X5.w, w1c[23], a3);
            a0 = fmaf(X6.x, w1c[24], a0); a1 = fmaf(X6.y, w1c[25], a1);
            a2 = fmaf(X6.z, w1c[26], a2); a3 = fmaf(X6.w, w1c[27], a3);
            a0 = fmaf(X7.x, w1c[28], a0); a1 = fmaf(X7.y, w1c[29], a1);
            a2 = fmaf(X7.z, w1c[30], a2); a3 = fmaf(X7.w, w1c[31], a3);
            const float dot = __fadd_rn(__fadd_rn(a0, a1), __fadd_rn(a2, a3));

            syn1 = __fadd_rn(__fmul_rn(A_SYN1, syn1), __fmul_rn(IN_SC1, dot));
            mem1 = __fadd_rn(__fmul_rn(A_MEM1, mem1), __fmul_rn(B_MEM1, syn1));
            const float s1v = (mem1 - TH1 > 0.0f) ? 1.0f : 0.0f;
            mem1 = __fsub_rn(mem1, __fmul_rn(s1v, TH1));

            if (act) {
                s1p[(size_t)(t0 + s) * HH] = s1v;
                m1p[(size_t)(t0 + s) * HH] = mem1;
            }

            float cx = s1v * w2x;
            float cy = s1v * w2y;
            wave_sum2(cx, cy);   // sequential per-step DPP tree (verified order)
            if (lane == 63)
                partv[sc & 1][s][wid] = make_float2(cx, cy);

            // rotate prefetched x into place (full unroll -> register renames)
            if (s < SC - 1) {
#pragma unroll
                for (int k = 0; k < 8; ++k) Xc[k] = Xn[k];
            }
        }

        // commit next chunk's x to the other LDS buffer (last sub-chunk of c)
        if (cpos == 56 && c + 1 < NCH) {
            if (2 * tid     < nfl4) xls[buf ^ 1][2 * tid]     = pr0;
            if (2 * tid + 1 < nfl4) xls[buf ^ 1][2 * tid + 1] = pr1;
        }

        __syncthreads();
    }

    // epilogue: layer-2 for the final sub-chunk
    layer2_chunk(NSC - 1);

    if (tid == 0) {
        outp[b * OO + 0] = (float)accx / 1000.0f;
        outp[b * OO + 1] = (float)accy / 1000.0f;
    }
}

extern "C" void kernel_launch(void* const* d_in, const int* in_sizes, int n_in,
                              void* d_out, int out_size, void* d_ws, size_t ws_size,
                              hipStream_t stream) {
    const float* x  = (const float*)d_in[0];   // [256,1000,32]
    const float* w1 = (const float*)d_in[1];   // [32,200]
    const float* w2 = (const float*)d_in[2];   // [200,2]
    float* out = (float*)d_out;

    dim3 grid(TB), block(256);
    hipLaunchKernelGGL(snn_fwd, grid, block, 0, stream, x, w1, w2, out);
}

// Round 8
// 355.505 us; speedup vs baseline: 2.3728x; 1.0183x over previous
//
#include <hip/hip_runtime.h>

// TwoLayerSNN forward: B=256, T=1000, D=32, H=200, O=2
// One block/batch, 256 threads (4 waves). Round 8 = round 7 (passing, 362us)
// with ONE change: __syncthreads() -> raw s_barrier + lgkmcnt(0)-only drain.
// The per-sub-chunk barrier only needs to order LDS traffic (partv, xls);
// the 16 global stores/wave do NOT need draining (no cross-thread global
// deps) — __syncthreads' implicit vmcnt(0) was stalling ~500cy per sub-chunk.
// Raw barrier + this exact per-step body was already validated in round 2.

constexpr int TB = 256;
constexpr int TT = 1000;
constexpr int DD = 32;
constexpr int HH = 200;
constexpr int OO = 2;
constexpr int CH = 64;                    // timesteps per x staging chunk (8 KB)
constexpr int NCH = (TT + CH - 1) / CH;   // 16
constexpr int SC = 8;                     // timesteps per barrier interval
constexpr int NSC = TT / SC;              // 125

__device__ __forceinline__ void wave_sum2(float& a, float& b) {
    // wave64 sum; result valid in lane 63 of each wave. (verified rounds 2/6/7)
#define DPP_STEP(CTRL)                                                          \
    {                                                                           \
        int ta = __builtin_amdgcn_update_dpp(0, __float_as_int(a), CTRL, 0xf, 0xf, true); \
        int tb = __builtin_amdgcn_update_dpp(0, __float_as_int(b), CTRL, 0xf, 0xf, true); \
        a += __int_as_float(ta);                                                \
        b += __int_as_float(tb);                                                \
    }
    DPP_STEP(0x111)  // row_shr:1
    DPP_STEP(0x112)  // row_shr:2
    DPP_STEP(0x114)  // row_shr:4
    DPP_STEP(0x118)  // row_shr:8
    DPP_STEP(0x142)  // row_bcast:15
    DPP_STEP(0x143)  // row_bcast:31
#undef DPP_STEP
}

__device__ __forceinline__ void block_sync_lds() {
    // Order LDS only: drain lgkm, then barrier. No vmcnt drain (global stores
    // in flight stay in flight). "memory" clobber pins LDS ops on each side.
    asm volatile("s_waitcnt lgkmcnt(0)" ::: "memory");
    __builtin_amdgcn_s_barrier();
    asm volatile("" ::: "memory");
}

__global__ __launch_bounds__(256, 1)
void snn_fwd(const float* __restrict__ x,
             const float* __restrict__ w1,
             const float* __restrict__ w2,
             float* __restrict__ out)
{
    const int b    = blockIdx.x;
    const int tid  = threadIdx.x;
    const int lane = tid & 63;
    const int wid  = tid >> 6;
    const bool act = tid < HH;

    float* __restrict__ outp = out;                        // [TB][OO]
    float* __restrict__ s1o  = out + (size_t)TB * OO;      // [TB][TT][HH]
    float* __restrict__ m1o  = s1o + (size_t)TB * TT * HH; // [TB][TT][HH]
    float* __restrict__ s2o  = m1o + (size_t)TB * TT * HH; // [TB][TT][OO]
    float* __restrict__ m2o  = s2o + (size_t)TB * TT * OO; // [TB][TT][OO]

    const float A_SYN1 = (float)0.8187307530779818;
    const float IN_SC1 = (float)((1.0 - 0.8187307530779818) * 5.0);
    const float A_MEM1 = (float)0.9048374180359595;
    const float B_MEM1 = (float)(1.0 - 0.9048374180359595);
    const float TH1    = 0.5f;
    const float A_SYN2 = (float)0.9048374180359595;
    const float IN_SC2 = (float)((1.0 - 0.9048374180359595) * 10.0);
    const float A_MEM2 = (float)0.9512294245007140;
    const float B_MEM2 = (float)(1.0 - 0.9512294245007140);
    const float TH2    = 1.0f;

    __shared__ float4 xls[2][CH * DD / 4];           // 2 x 8 KB
    __shared__ __align__(16) float2 partv[2][SC][4]; // parity x step x wave

    const float* __restrict__ xb = x + (size_t)b * TT * DD;

    float w1c[DD];
#pragma unroll
    for (int d = 0; d < DD; ++d) w1c[d] = act ? w1[d * HH + tid] : 0.0f;
    const float w2x = act ? w2[tid * OO + 0] : 0.0f;
    const float w2y = act ? w2[tid * OO + 1] : 0.0f;

    // stage chunk 0 (full 8 KB): 2 float4 per thread
    {
        const float4* g = (const float4*)xb;
        xls[0][2 * tid]     = g[2 * tid];
        xls[0][2 * tid + 1] = g[2 * tid + 1];
    }
    block_sync_lds();

    float syn1 = 0.0f, mem1 = 0.0f;
    float syn2x = 0.0f, syn2y = 0.0f, mem2x = 0.0f, mem2y = 0.0f;
    double accx = 0.0, accy = 0.0;

    // PERSISTENT staging state (must outlive the loading iteration)
    float4 pr0 = make_float4(0.f, 0.f, 0.f, 0.f);
    float4 pr1 = make_float4(0.f, 0.f, 0.f, 0.f);
    int nfl4 = 0;

    float* __restrict__ s1p = s1o + (size_t)b * TT * HH + tid;
    float* __restrict__ m1p = m1o + (size_t)b * TT * HH + tid;
    float2* __restrict__ s2p = (float2*)(s2o + (size_t)b * TT * OO);
    float2* __restrict__ m2p = (float2*)(m2o + (size_t)b * TT * OO);

    // epilogue-only layer-2 (reads partv from LDS; identical chain)
    auto layer2_chunk = [&](int j) {
#pragma unroll
        for (int s = 0; s < SC; ++s) {
            const float4* pv = (const float4*)&partv[j & 1][s][0];
            const float4 q0 = pv[0];
            const float4 q1 = pv[1];
            const float dx = __fadd_rn(__fadd_rn(q0.x, q0.z), __fadd_rn(q1.x, q1.z));
            const float dy = __fadd_rn(__fadd_rn(q0.y, q0.w), __fadd_rn(q1.y, q1.w));
            syn2x = __fadd_rn(__fmul_rn(A_SYN2, syn2x), __fmul_rn(IN_SC2, dx));
            syn2y = __fadd_rn(__fmul_rn(A_SYN2, syn2y), __fmul_rn(IN_SC2, dy));
            mem2x = __fadd_rn(__fmul_rn(A_MEM2, mem2x), __fmul_rn(B_MEM2, syn2x));
            mem2y = __fadd_rn(__fmul_rn(A_MEM2, mem2y), __fmul_rn(B_MEM2, syn2y));
            const float s2x = (mem2x - TH2 > 0.0f) ? 1.0f : 0.0f;
            const float s2y = (mem2y - TH2 > 0.0f) ? 1.0f : 0.0f;
            mem2x = __fsub_rn(mem2x, __fmul_rn(s2x, TH2));
            mem2y = __fsub_rn(mem2y, __fmul_rn(s2y, TH2));
            const int t = j * SC + s;
            if (tid == 0) {
                s2p[t] = make_float2(s2x, s2y);
                m2p[t] = make_float2(mem2x, mem2y);
            }
            if (t > 0) { accx += (double)mem2x; accy += (double)mem2y; }
        }
    };

    for (int sc = 0; sc < NSC; ++sc) {
        const int t0   = sc * SC;
        const int c    = t0 >> 6;
        const int buf  = c & 1;
        const int cpos = t0 & 63;

        // ---- top-of-subchunk load burst ----
        // partv of the PREVIOUS parity (written before the last barrier)
        float4 P[16];
        {
            const float4* pvall = (const float4*)&partv[(sc + 1) & 1][0][0];
#pragma unroll
            for (int i = 0; i < 16; ++i) P[i] = pvall[i];
        }
        // step-0 x block
        const float4* xp = &xls[buf][cpos * (DD / 4)];
        float4 Xc[8];
#pragma unroll
        for (int k = 0; k < 8; ++k) Xc[k] = xp[k];

        // staging: first sub-chunk of chunk c loads chunk c+1 (persistent regs)
        if (cpos == 0 && c + 1 < NCH) {
            const int nst = (CH < TT - (c + 1) * CH) ? CH : (TT - (c + 1) * CH);
            nfl4 = nst * DD / 4;
            const float4* g = (const float4*)(xb + (size_t)(c + 1) * CH * DD);
            if (2 * tid     < nfl4) pr0 = g[2 * tid];
            if (2 * tid + 1 < nfl4) pr1 = g[2 * tid + 1];
        }

        // ---- layer-2 for previous sub-chunk, from registers ----
        if (sc > 0) {
#pragma unroll
            for (int s = 0; s < SC; ++s) {
                const float4 q0 = P[2 * s];
                const float4 q1 = P[2 * s + 1];
                const float dx = __fadd_rn(__fadd_rn(q0.x, q0.z), __fadd_rn(q1.x, q1.z));
                const float dy = __fadd_rn(__fadd_rn(q0.y, q0.w), __fadd_rn(q1.y, q1.w));
                syn2x = __fadd_rn(__fmul_rn(A_SYN2, syn2x), __fmul_rn(IN_SC2, dx));
                syn2y = __fadd_rn(__fmul_rn(A_SYN2, syn2y), __fmul_rn(IN_SC2, dy));
                mem2x = __fadd_rn(__fmul_rn(A_MEM2, mem2x), __fmul_rn(B_MEM2, syn2x));
                mem2y = __fadd_rn(__fmul_rn(A_MEM2, mem2y), __fmul_rn(B_MEM2, syn2y));
                const float s2x = (mem2x - TH2 > 0.0f) ? 1.0f : 0.0f;
                const float s2y = (mem2y - TH2 > 0.0f) ? 1.0f : 0.0f;
                mem2x = __fsub_rn(mem2x, __fmul_rn(s2x, TH2));
                mem2y = __fsub_rn(mem2y, __fmul_rn(s2y, TH2));
                const int t = (sc - 1) * SC + s;
                if (tid == 0) {
                    s2p[t] = make_float2(s2x, s2y);
                    m2p[t] = make_float2(mem2x, mem2y);
                }
                if (t > 0) { accx += (double)mem2x; accy += (double)mem2y; }
            }
        }

        // ---- 8 steps; per-step body textually round 6/7's; x via rotation ----
#pragma unroll
        for (int s = 0; s < SC; ++s) {
            // prefetch next step's x block (latency hides under this step)
            float4 Xn[8];
            if (s < SC - 1) {
#pragma unroll
                for (int k = 0; k < 8; ++k) Xn[k] = xp[(s + 1) * 8 + k];
            }

            const float4 X0 = Xc[0], X1 = Xc[1], X2 = Xc[2], X3 = Xc[3];
            const float4 X4 = Xc[4], X5 = Xc[5], X6 = Xc[6], X7 = Xc[7];

            float a0 = 0.f, a1 = 0.f, a2 = 0.f, a3 = 0.f;
            a0 = fmaf(X0.x, w1c[0],  a0); a1 = fmaf(X0.y, w1c[1],  a1);
            a2 = fmaf(X0.z, w1c[2],  a2); a3 = fmaf(X0.w, w1c[3],  a3);
            a0 = fmaf(X1.x, w1c[4],  a0); a1 = fmaf(X1.y, w1c[5],  a1);
            a2 = fmaf(X1.z, w1c[6],  a2); a3 = fmaf(X1.w, w1c[7],  a3);
            a0 = fmaf(X2.x, w1c[8],  a0); a1 = fmaf(X2.y, w1c[9],  a1);
            a2 = fmaf(X2.z, w1c[10], a2); a3 = fmaf(X2.w, w1c[11], a3);
            a0 = fmaf(X3.x, w1c[12], a0); a1 = fmaf(X3.y, w1c[13], a1);
            a2 = fmaf(X3.z, w1c[14], a2); a3 = fmaf(X3.w, w1c[15], a3);
            a0 = fmaf(X4.x, w1c[16], a0); a1 = fmaf(X4.y, w1c[17], a1);
            a2 = fmaf(X4.z, w1c[18], a2); a3 = fmaf(X4.w, w1c[19], a3);
            a0 = fmaf(X5.x, w1c[20], a0); a1 = fmaf(X5.y, w1c[21], a1);
            a2 = fmaf(X5.z, w1c[22], a2); a3 = fmaf(X5.w, w1c[23], a3);
            a0 = fmaf(X6.x, w1c[24], a0); a1 = fmaf(X6.y, w1c[25], a1);
            a2 = fmaf(X6.z, w1c[26], a2); a3 = fmaf(X6.w, w1c[27], a3);
            a0 = fmaf(X7.x, w1c[28], a0); a1 = fmaf(X7.y, w1c[29], a1);
            a2 = fmaf(X7.z, w1c[30], a2); a3 = fmaf(X7.w, w1c[31], a3);
            const float dot = __fadd_rn(__fadd_rn(a0, a1), __fadd_rn(a2, a3));

            syn1 = __fadd_rn(__fmul_rn(A_SYN1, syn1), __fmul_rn(IN_SC1, dot));
            mem1 = __fadd_rn(__fmul_rn(A_MEM1, mem1), __fmul_rn(B_MEM1, syn1));
            const float s1v = (mem1 - TH1 > 0.0f) ? 1.0f : 0.0f;
            mem1 = __fsub_rn(mem1, __fmul_rn(s1v, TH1));

            if (act) {
                s1p[(size_t)(t0 + s) * HH] = s1v;
                m1p[(size_t)(t0 + s) * HH] = mem1;
            }

            float cx = s1v * w2x;
            float cy = s1v * w2y;
            wave_sum2(cx, cy);   // sequential per-step DPP tree (verified order)
            if (lane == 63)
                partv[sc & 1][s][wid] = make_float2(cx, cy);

            // rotate prefetched x into place (full unroll -> register renames)
            if (s < SC - 1) {
#pragma unroll
                for (int k = 0; k < 8; ++k) Xc[k] = Xn[k];
            }
        }

        // commit next chunk's x to the other LDS buffer (last sub-chunk of c)
        if (cpos == 56 && c + 1 < NCH) {
            if (2 * tid     < nfl4) xls[buf ^ 1][2 * tid]     = pr0;
            if (2 * tid + 1 < nfl4) xls[buf ^ 1][2 * tid + 1] = pr1;
        }

        block_sync_lds();
    }

    // epilogue: layer-2 for the final sub-chunk
    layer2_chunk(NSC - 1);

    if (tid == 0) {
        outp[b * OO + 0] = (float)accx / 1000.0f;
        outp[b * OO + 1] = (float)accy / 1000.0f;
    }
}

extern "C" void kernel_launch(void* const* d_in, const int* in_sizes, int n_in,
                              void* d_out, int out_size, void* d_ws, size_t ws_size,
                              hipStream_t stream) {
    const float* x  = (const float*)d_in[0];   // [256,1000,32]
    const float* w1 = (const float*)d_in[1];   // [32,200]
    const float* w2 = (const float*)d_in[2];   // [200,2]
    float* out = (float*)d_out;

    dim3 grid(TB), block(256);
    hipLaunchKernelGGL(snn_fwd, grid, block, 0, stream, x, w1, w2, out);
}

// Round 9
// 245.960 us; speedup vs baseline: 3.4296x; 1.4454x over previous
//
#include <hip/hip_runtime.h>

// TwoLayerSNN forward: B=256, T=1000, D=32, H=200, O=2
// Round 9: producer/consumer wave specialization. 512 threads (8 waves):
//   waves 0-3 (consumers): r8's recurrence + stores + DPP + layer-2, with
//     dot[t][h] READ from an LDS double buffer instead of computed.
//   waves 4-7 (producers): compute the NEXT sub-chunk's dots (bit-identical
//     fmaf chain, 50 h per wave) into the LDS dot buffer; own x staging.
// 2 waves/SIMD -> stalls of one wave hidden by the other (was 1 wave/SIMD,
// VALUBusy capped ~40%). All arithmetic bit-identical to round 8.

constexpr int TB = 256;
constexpr int TT = 1000;
constexpr int DD = 32;
constexpr int HH = 200;
constexpr int OO = 2;
constexpr int CH = 64;                    // timesteps per x staging chunk (8 KB)
constexpr int NCH = (TT + CH - 1) / CH;   // 16
constexpr int SC = 8;                     // timesteps per barrier interval
constexpr int NSC = TT / SC;              // 125

__device__ __forceinline__ void wave_sum2(float& a, float& b) {
    // wave64 sum; result valid in lane 63 of each wave. (verified r2/6/7/8)
#define DPP_STEP(CTRL)                                                          \
    {                                                                           \
        int ta = __builtin_amdgcn_update_dpp(0, __float_as_int(a), CTRL, 0xf, 0xf, true); \
        int tb = __builtin_amdgcn_update_dpp(0, __float_as_int(b), CTRL, 0xf, 0xf, true); \
        a += __int_as_float(ta);                                                \
        b += __int_as_float(tb);                                                \
    }
    DPP_STEP(0x111)  // row_shr:1
    DPP_STEP(0x112)  // row_shr:2
    DPP_STEP(0x114)  // row_shr:4
    DPP_STEP(0x118)  // row_shr:8
    DPP_STEP(0x142)  // row_bcast:15
    DPP_STEP(0x143)  // row_bcast:31
#undef DPP_STEP
}

__device__ __forceinline__ void block_sync_lds() {
    // Order LDS only (validated r8): drain lgkm, raw barrier, no vmcnt drain.
    asm volatile("s_waitcnt lgkmcnt(0)" ::: "memory");
    __builtin_amdgcn_s_barrier();
    asm volatile("" ::: "memory");
}

__global__ __launch_bounds__(512, 1)
void snn_fwd(const float* __restrict__ x,
             const float* __restrict__ w1,
             const float* __restrict__ w2,
             float* __restrict__ out)
{
    const int b    = blockIdx.x;
    const int tid  = threadIdx.x;
    const int lane = tid & 63;
    const int wid  = tid >> 6;
    const bool is_cons = (wid < 4);        // waves 0-3 consume, 4-7 produce
    const int ptid = tid - 256;            // producer-local 0..255
    const bool act = is_cons && (tid < HH);

    float* __restrict__ outp = out;                        // [TB][OO]
    float* __restrict__ s1o  = out + (size_t)TB * OO;      // [TB][TT][HH]
    float* __restrict__ m1o  = s1o + (size_t)TB * TT * HH; // [TB][TT][HH]
    float* __restrict__ s2o  = m1o + (size_t)TB * TT * HH; // [TB][TT][OO]
    float* __restrict__ m2o  = s2o + (size_t)TB * TT * OO; // [TB][TT][OO]

    const float A_SYN1 = (float)0.8187307530779818;
    const float IN_SC1 = (float)((1.0 - 0.8187307530779818) * 5.0);
    const float A_MEM1 = (float)0.9048374180359595;
    const float B_MEM1 = (float)(1.0 - 0.9048374180359595);
    const float TH1    = 0.5f;
    const float A_SYN2 = (float)0.9048374180359595;
    const float IN_SC2 = (float)((1.0 - 0.9048374180359595) * 10.0);
    const float A_MEM2 = (float)0.9512294245007140;
    const float B_MEM2 = (float)(1.0 - 0.9512294245007140);
    const float TH2    = 1.0f;

    __shared__ float4 xls[2][CH * DD / 4];           // 2 x 8 KB
    __shared__ float  dotb[2][SC][HH];               // dot dbuf, 6.4 KB ea
    __shared__ __align__(16) float2 partv[2][SC][4]; // parity x step x wave

    const float* __restrict__ xb = x + (size_t)b * TT * DD;

    // producer: 50 hidden units per wave; w1 column in registers
    const int ph   = (wid - 4) * 50 + lane;          // producer h
    const bool pact = (!is_cons) && (lane < 50);
    float w1c[DD];
#pragma unroll
    for (int d = 0; d < DD; ++d) w1c[d] = pact ? w1[d * HH + ph] : 0.0f;
    // consumer: w2 row
    const float w2x = act ? w2[tid * OO + 0] : 0.0f;
    const float w2y = act ? w2[tid * OO + 1] : 0.0f;

    // stage chunk 0 (8 KB) using consumer threads (one-time)
    if (is_cons) {
        const float4* g = (const float4*)xb;
        xls[0][2 * tid]     = g[2 * tid];
        xls[0][2 * tid + 1] = g[2 * tid + 1];
    }
    block_sync_lds();

    // produce(j): dots for sub-chunk j into dotb[j&1]; bit-identical chain.
    auto produce = [&](int j) {
        const int tj = j * SC;
        const float4* xq = &xls[(tj >> 6) & 1][(tj & 63) * (DD / 4)];
#pragma unroll
        for (int s = 0; s < SC; ++s) {
            const float4 X0 = xq[s * 8 + 0], X1 = xq[s * 8 + 1];
            const float4 X2 = xq[s * 8 + 2], X3 = xq[s * 8 + 3];
            const float4 X4 = xq[s * 8 + 4], X5 = xq[s * 8 + 5];
            const float4 X6 = xq[s * 8 + 6], X7 = xq[s * 8 + 7];
            float a0 = 0.f, a1 = 0.f, a2 = 0.f, a3 = 0.f;
            a0 = fmaf(X0.x, w1c[0],  a0); a1 = fmaf(X0.y, w1c[1],  a1);
            a2 = fmaf(X0.z, w1c[2],  a2); a3 = fmaf(X0.w, w1c[3],  a3);
            a0 = fmaf(X1.x, w1c[4],  a0); a1 = fmaf(X1.y, w1c[5],  a1);
            a2 = fmaf(X1.z, w1c[6],  a2); a3 = fmaf(X1.w, w1c[7],  a3);
            a0 = fmaf(X2.x, w1c[8],  a0); a1 = fmaf(X2.y, w1c[9],  a1);
            a2 = fmaf(X2.z, w1c[10], a2); a3 = fmaf(X2.w, w1c[11], a3);
            a0 = fmaf(X3.x, w1c[12], a0); a1 = fmaf(X3.y, w1c[13], a1);
            a2 = fmaf(X3.z, w1c[14], a2); a3 = fmaf(X3.w, w1c[15], a3);
            a0 = fmaf(X4.x, w1c[16], a0); a1 = fmaf(X4.y, w1c[17], a1);
            a2 = fmaf(X4.z, w1c[18], a2); a3 = fmaf(X4.w, w1c[19], a3);
            a0 = fmaf(X5.x, w1c[20], a0); a1 = fmaf(X5.y, w1c[21], a1);
            a2 = fmaf(X5.z, w1c[22], a2); a3 = fmaf(X5.w, w1c[23], a3);
            a0 = fmaf(X6.x, w1c[24], a0); a1 = fmaf(X6.y, w1c[25], a1);
            a2 = fmaf(X6.z, w1c[26], a2); a3 = fmaf(X6.w, w1c[27], a3);
            a0 = fmaf(X7.x, w1c[28], a0); a1 = fmaf(X7.y, w1c[29], a1);
            a2 = fmaf(X7.z, w1c[30], a2); a3 = fmaf(X7.w, w1c[31], a3);
            const float dotv = __fadd_rn(__fadd_rn(a0, a1), __fadd_rn(a2, a3));
            if (pact) dotb[j & 1][s][ph] = dotv;
        }
    };

    // prologue: fill dotb[0] for sub-chunk 0
    if (!is_cons) produce(0);
    block_sync_lds();

    float syn1 = 0.0f, mem1 = 0.0f;
    float syn2x = 0.0f, syn2y = 0.0f, mem2x = 0.0f, mem2y = 0.0f;
    double accx = 0.0, accy = 0.0;

    // PERSISTENT producer staging state (must outlive the loading iteration)
    float4 pr0 = make_float4(0.f, 0.f, 0.f, 0.f);
    float4 pr1 = make_float4(0.f, 0.f, 0.f, 0.f);
    int nfl4 = 0;

    float* __restrict__ s1p = s1o + (size_t)b * TT * HH + tid;
    float* __restrict__ m1p = m1o + (size_t)b * TT * HH + tid;
    float2* __restrict__ s2p = (float2*)(s2o + (size_t)b * TT * OO);
    float2* __restrict__ m2p = (float2*)(m2o + (size_t)b * TT * OO);

    // epilogue-only layer-2 (reads partv from LDS; identical chain)
    auto layer2_chunk = [&](int j) {
#pragma unroll
        for (int s = 0; s < SC; ++s) {
            const float4* pv = (const float4*)&partv[j & 1][s][0];
            const float4 q0 = pv[0];
            const float4 q1 = pv[1];
            const float dx = __fadd_rn(__fadd_rn(q0.x, q0.z), __fadd_rn(q1.x, q1.z));
            const float dy = __fadd_rn(__fadd_rn(q0.y, q0.w), __fadd_rn(q1.y, q1.w));
            syn2x = __fadd_rn(__fmul_rn(A_SYN2, syn2x), __fmul_rn(IN_SC2, dx));
            syn2y = __fadd_rn(__fmul_rn(A_SYN2, syn2y), __fmul_rn(IN_SC2, dy));
            mem2x = __fadd_rn(__fmul_rn(A_MEM2, mem2x), __fmul_rn(B_MEM2, syn2x));
            mem2y = __fadd_rn(__fmul_rn(A_MEM2, mem2y), __fmul_rn(B_MEM2, syn2y));
            const float s2x = (mem2x - TH2 > 0.0f) ? 1.0f : 0.0f;
            const float s2y = (mem2y - TH2 > 0.0f) ? 1.0f : 0.0f;
            mem2x = __fsub_rn(mem2x, __fmul_rn(s2x, TH2));
            mem2y = __fsub_rn(mem2y, __fmul_rn(s2y, TH2));
            const int t = j * SC + s;
            if (tid == 0) {
                s2p[t] = make_float2(s2x, s2y);
                m2p[t] = make_float2(mem2x, mem2y);
            }
            if (t > 0) { accx += (double)mem2x; accy += (double)mem2y; }
        }
    };

    for (int sc = 0; sc < NSC; ++sc) {
        const int t0   = sc * SC;
        const int c    = t0 >> 6;
        const int cpos = t0 & 63;

        if (is_cons) {
            // ---- consumer: burst-read partv (prev parity) + this chunk's dots
            float4 P[16];
            {
                const float4* pvall = (const float4*)&partv[(sc + 1) & 1][0][0];
#pragma unroll
                for (int i = 0; i < 16; ++i) P[i] = pvall[i];
            }
            float D[SC];
#pragma unroll
            for (int s = 0; s < SC; ++s) D[s] = dotb[sc & 1][s][tid];

            // layer-2 for previous sub-chunk, from registers (r7/r8 verified)
            if (sc > 0) {
#pragma unroll
                for (int s = 0; s < SC; ++s) {
                    const float4 q0 = P[2 * s];
                    const float4 q1 = P[2 * s + 1];
                    const float dx = __fadd_rn(__fadd_rn(q0.x, q0.z), __fadd_rn(q1.x, q1.z));
                    const float dy = __fadd_rn(__fadd_rn(q0.y, q0.w), __fadd_rn(q1.y, q1.w));
                    syn2x = __fadd_rn(__fmul_rn(A_SYN2, syn2x), __fmul_rn(IN_SC2, dx));
                    syn2y = __fadd_rn(__fmul_rn(A_SYN2, syn2y), __fmul_rn(IN_SC2, dy));
                    mem2x = __fadd_rn(__fmul_rn(A_MEM2, mem2x), __fmul_rn(B_MEM2, syn2x));
                    mem2y = __fadd_rn(__fmul_rn(A_MEM2, mem2y), __fmul_rn(B_MEM2, syn2y));
                    const float s2x = (mem2x - TH2 > 0.0f) ? 1.0f : 0.0f;
                    const float s2y = (mem2y - TH2 > 0.0f) ? 1.0f : 0.0f;
                    mem2x = __fsub_rn(mem2x, __fmul_rn(s2x, TH2));
                    mem2y = __fsub_rn(mem2y, __fmul_rn(s2y, TH2));
                    const int t = (sc - 1) * SC + s;
                    if (tid == 0) {
                        s2p[t] = make_float2(s2x, s2y);
                        m2p[t] = make_float2(mem2x, mem2y);
                    }
                    if (t > 0) { accx += (double)mem2x; accy += (double)mem2y; }
                }
            }

            // ---- 8 steps: recurrence + stores + DPP (textually r8's) ----
#pragma unroll
            for (int s = 0; s < SC; ++s) {
                const float dot = D[s];
                syn1 = __fadd_rn(__fmul_rn(A_SYN1, syn1), __fmul_rn(IN_SC1, dot));
                mem1 = __fadd_rn(__fmul_rn(A_MEM1, mem1), __fmul_rn(B_MEM1, syn1));
                const float s1v = (mem1 - TH1 > 0.0f) ? 1.0f : 0.0f;
                mem1 = __fsub_rn(mem1, __fmul_rn(s1v, TH1));

                if (act) {
                    s1p[(size_t)(t0 + s) * HH] = s1v;
                    m1p[(size_t)(t0 + s) * HH] = mem1;
                }

                float cx = s1v * w2x;
                float cy = s1v * w2y;
                wave_sum2(cx, cy);
                if (lane == 63)
                    partv[sc & 1][s][wid] = make_float2(cx, cy);
            }
        } else {
            // ---- producer: stage x chunks; compute next sub-chunk's dots ----
            if (cpos == 0 && c + 1 < NCH) {
                const int nst = (CH < TT - (c + 1) * CH) ? CH : (TT - (c + 1) * CH);
                nfl4 = nst * DD / 4;
                const float4* g = (const float4*)(xb + (size_t)(c + 1) * CH * DD);
                if (2 * ptid     < nfl4) pr0 = g[2 * ptid];
                if (2 * ptid + 1 < nfl4) pr1 = g[2 * ptid + 1];
            }

            if (sc + 1 < NSC) produce(sc + 1);

            // commit chunk c+1 before producers first read it (at cpos 56)
            if (cpos == 48 && c + 1 < NCH) {
                if (2 * ptid     < nfl4) xls[(c + 1) & 1][2 * ptid]     = pr0;
                if (2 * ptid + 1 < nfl4) xls[(c + 1) & 1][2 * ptid + 1] = pr1;
            }
        }

        block_sync_lds();
    }

    // epilogue: layer-2 for the final sub-chunk
    if (is_cons) {
        layer2_chunk(NSC - 1);
        if (tid == 0) {
            outp[b * OO + 0] = (float)accx / 1000.0f;
            outp[b * OO + 1] = (float)accy / 1000.0f;
        }
    }
}

extern "C" void kernel_launch(void* const* d_in, const int* in_sizes, int n_in,
                              void* d_out, int out_size, void* d_ws, size_t ws_size,
                              hipStream_t stream) {
    const float* x  = (const float*)d_in[0];   // [256,1000,32]
    const float* w1 = (const float*)d_in[1];   // [32,200]
    const float* w2 = (const float*)d_in[2];   // [200,2]
    float* out = (float*)d_out;

    dim3 grid(TB), block(512);
    hipLaunchKernelGGL(snn_fwd, grid, block, 0, stream, x, w1, w2, out);
}

// Round 10
// 196.720 us; speedup vs baseline: 4.2881x; 1.2503x over previous
//
#include <hip/hip_runtime.h>

// TwoLayerSNN forward: B=256, T=1000, D=32, H=200, O=2
// Round 10 = round 9 (passing, 246us) with two instruction-count cuts:
//  (1) producer dots use v_pk_fma_f32 (float2 ext-vector) with the SAME
//      accumulator pairing (a0,a1)/(a2,a3) -> bit-identical, half the fmas.
//  (2) layer-2 moves off the 4 consumer waves onto a dedicated 9th wave
//      (block 576): consumers drop the replicated P-burst + chain entirely.
// Roles: waves 0-3 consume (recurrence/stores/DPP), 4-7 produce dots + stage
// x, wave 8 runs layer-2 lagged one sub-chunk. All handoffs parity-double-
// buffered and barrier-separated exactly as validated in round 9.

constexpr int TB = 256;
constexpr int TT = 1000;
constexpr int DD = 32;
constexpr int HH = 200;
constexpr int OO = 2;
constexpr int CH = 64;                    // timesteps per x staging chunk (8 KB)
constexpr int NCH = (TT + CH - 1) / CH;   // 16
constexpr int SC = 8;                     // timesteps per barrier interval
constexpr int NSC = TT / SC;              // 125

typedef float v2f __attribute__((ext_vector_type(2)));

__device__ __forceinline__ v2f pk_fma(v2f a, v2f b, v2f c) {
#if __has_builtin(__builtin_elementwise_fma)
    return __builtin_elementwise_fma(a, b, c);
#else
    v2f r; r.x = fmaf(a.x, b.x, c.x); r.y = fmaf(a.y, b.y, c.y); return r;
#endif
}

__device__ __forceinline__ void wave_sum2(float& a, float& b) {
    // wave64 sum; result valid in lane 63 of each wave. (verified r2/6/7/8/9)
#define DPP_STEP(CTRL)                                                          \
    {                                                                           \
        int ta = __builtin_amdgcn_update_dpp(0, __float_as_int(a), CTRL, 0xf, 0xf, true); \
        int tb = __builtin_amdgcn_update_dpp(0, __float_as_int(b), CTRL, 0xf, 0xf, true); \
        a += __int_as_float(ta);                                                \
        b += __int_as_float(tb);                                                \
    }
    DPP_STEP(0x111)  // row_shr:1
    DPP_STEP(0x112)  // row_shr:2
    DPP_STEP(0x114)  // row_shr:4
    DPP_STEP(0x118)  // row_shr:8
    DPP_STEP(0x142)  // row_bcast:15
    DPP_STEP(0x143)  // row_bcast:31
#undef DPP_STEP
}

__device__ __forceinline__ void block_sync_lds() {
    // Order LDS only (validated r8/r9): drain lgkm, raw barrier, no vmcnt drain.
    asm volatile("s_waitcnt lgkmcnt(0)" ::: "memory");
    __builtin_amdgcn_s_barrier();
    asm volatile("" ::: "memory");
}

__global__ __launch_bounds__(576, 1)
void snn_fwd(const float* __restrict__ x,
             const float* __restrict__ w1,
             const float* __restrict__ w2,
             float* __restrict__ out)
{
    const int b    = blockIdx.x;
    const int tid  = threadIdx.x;
    const int lane = tid & 63;
    const int wid  = tid >> 6;
    const bool is_cons = (wid < 4);        // waves 0-3: consumers
    const bool is_prod = (wid >= 4 && wid < 8); // waves 4-7: producers
    const int ptid = tid - 256;            // producer-local 0..255
    const bool act = is_cons && (tid < HH);

    float* __restrict__ outp = out;                        // [TB][OO]
    float* __restrict__ s1o  = out + (size_t)TB * OO;      // [TB][TT][HH]
    float* __restrict__ m1o  = s1o + (size_t)TB * TT * HH; // [TB][TT][HH]
    float* __restrict__ s2o  = m1o + (size_t)TB * TT * HH; // [TB][TT][OO]
    float* __restrict__ m2o  = s2o + (size_t)TB * TT * OO; // [TB][TT][OO]

    const float A_SYN1 = (float)0.8187307530779818;
    const float IN_SC1 = (float)((1.0 - 0.8187307530779818) * 5.0);
    const float A_MEM1 = (float)0.9048374180359595;
    const float B_MEM1 = (float)(1.0 - 0.9048374180359595);
    const float TH1    = 0.5f;
    const float A_SYN2 = (float)0.9048374180359595;
    const float IN_SC2 = (float)((1.0 - 0.9048374180359595) * 10.0);
    const float A_MEM2 = (float)0.9512294245007140;
    const float B_MEM2 = (float)(1.0 - 0.9512294245007140);
    const float TH2    = 1.0f;

    __shared__ float4 xls[2][CH * DD / 4];           // 2 x 8 KB
    __shared__ float  dotb[2][SC][HH];               // dot dbuf, 6.4 KB ea
    __shared__ __align__(16) float2 partv[2][SC][4]; // parity x step x wave

    const float* __restrict__ xb = x + (size_t)b * TT * DD;

    // producer: 50 hidden units per wave; w1 column as 16 float2 pairs
    const int ph   = (wid - 4) * 50 + lane;          // producer h
    const bool pact = is_prod && (lane < 50);
    v2f w1e[DD / 4], w1o[DD / 4];
#pragma unroll
    for (int i = 0; i < DD / 4; ++i) {
        w1e[i] = pact ? v2f{w1[(4 * i) * HH + ph],     w1[(4 * i + 1) * HH + ph]} : v2f{0.f, 0.f};
        w1o[i] = pact ? v2f{w1[(4 * i + 2) * HH + ph], w1[(4 * i + 3) * HH + ph]} : v2f{0.f, 0.f};
    }
    // consumer: w2 row
    const float w2x = act ? w2[tid * OO + 0] : 0.0f;
    const float w2y = act ? w2[tid * OO + 1] : 0.0f;

    // stage chunk 0 (8 KB) using consumer threads (one-time)
    if (is_cons) {
        const float4* g = (const float4*)xb;
        xls[0][2 * tid]     = g[2 * tid];
        xls[0][2 * tid + 1] = g[2 * tid + 1];
    }
    block_sync_lds();

    // produce(j): dots for sub-chunk j into dotb[j&1].
    // Bit-identical to r9: pk lanes carry (a0,a1) and (a2,a3) exactly.
    auto produce = [&](int j) {
        const int tj = j * SC;
        const float4* xq = &xls[(tj >> 6) & 1][(tj & 63) * (DD / 4)];
#pragma unroll
        for (int s = 0; s < SC; ++s) {
            const float4 X0 = xq[s * 8 + 0], X1 = xq[s * 8 + 1];
            const float4 X2 = xq[s * 8 + 2], X3 = xq[s * 8 + 3];
            const float4 X4 = xq[s * 8 + 4], X5 = xq[s * 8 + 5];
            const float4 X6 = xq[s * 8 + 6], X7 = xq[s * 8 + 7];
            v2f A01 = {0.f, 0.f}, A23 = {0.f, 0.f};
            A01 = pk_fma(v2f{X0.x, X0.y}, w1e[0], A01);
            A23 = pk_fma(v2f{X0.z, X0.w}, w1o[0], A23);
            A01 = pk_fma(v2f{X1.x, X1.y}, w1e[1], A01);
            A23 = pk_fma(v2f{X1.z, X1.w}, w1o[1], A23);
            A01 = pk_fma(v2f{X2.x, X2.y}, w1e[2], A01);
            A23 = pk_fma(v2f{X2.z, X2.w}, w1o[2], A23);
            A01 = pk_fma(v2f{X3.x, X3.y}, w1e[3], A01);
            A23 = pk_fma(v2f{X3.z, X3.w}, w1o[3], A23);
            A01 = pk_fma(v2f{X4.x, X4.y}, w1e[4], A01);
            A23 = pk_fma(v2f{X4.z, X4.w}, w1o[4], A23);
            A01 = pk_fma(v2f{X5.x, X5.y}, w1e[5], A01);
            A23 = pk_fma(v2f{X5.z, X5.w}, w1o[5], A23);
            A01 = pk_fma(v2f{X6.x, X6.y}, w1e[6], A01);
            A23 = pk_fma(v2f{X6.z, X6.w}, w1o[6], A23);
            A01 = pk_fma(v2f{X7.x, X7.y}, w1e[7], A01);
            A23 = pk_fma(v2f{X7.z, X7.w}, w1o[7], A23);
            const float dotv = __fadd_rn(__fadd_rn(A01.x, A01.y),
                                         __fadd_rn(A23.x, A23.y));
            if (pact) dotb[j & 1][s][ph] = dotv;
        }
    };

    // prologue: fill dotb[0] for sub-chunk 0
    if (is_prod) produce(0);
    block_sync_lds();

    float syn1 = 0.0f, mem1 = 0.0f;
    float syn2x = 0.0f, syn2y = 0.0f, mem2x = 0.0f, mem2y = 0.0f;
    double accx = 0.0, accy = 0.0;

    // PERSISTENT producer staging state (must outlive the loading iteration)
    float4 pr0 = make_float4(0.f, 0.f, 0.f, 0.f);
    float4 pr1 = make_float4(0.f, 0.f, 0.f, 0.f);
    int nfl4 = 0;

    float* __restrict__ s1p = s1o + (size_t)b * TT * HH + tid;
    float* __restrict__ m1p = m1o + (size_t)b * TT * HH + tid;
    float2* __restrict__ s2p = (float2*)(s2o + (size_t)b * TT * OO);
    float2* __restrict__ m2p = (float2*)(m2o + (size_t)b * TT * OO);

    // layer-2 for sub-chunk j (wave 8 only; burst-reads partv[j&1] from LDS)
    auto l2_chunk = [&](int j) {
        float4 P[16];
        const float4* pvall = (const float4*)&partv[j & 1][0][0];
#pragma unroll
        for (int i = 0; i < 16; ++i) P[i] = pvall[i];
#pragma unroll
        for (int s = 0; s < SC; ++s) {
            const float4 q0 = P[2 * s];
            const float4 q1 = P[2 * s + 1];
            const float dx = __fadd_rn(__fadd_rn(q0.x, q0.z), __fadd_rn(q1.x, q1.z));
            const float dy = __fadd_rn(__fadd_rn(q0.y, q0.w), __fadd_rn(q1.y, q1.w));
            syn2x = __fadd_rn(__fmul_rn(A_SYN2, syn2x), __fmul_rn(IN_SC2, dx));
            syn2y = __fadd_rn(__fmul_rn(A_SYN2, syn2y), __fmul_rn(IN_SC2, dy));
            mem2x = __fadd_rn(__fmul_rn(A_MEM2, mem2x), __fmul_rn(B_MEM2, syn2x));
            mem2y = __fadd_rn(__fmul_rn(A_MEM2, mem2y), __fmul_rn(B_MEM2, syn2y));
            const float s2x = (mem2x - TH2 > 0.0f) ? 1.0f : 0.0f;
            const float s2y = (mem2y - TH2 > 0.0f) ? 1.0f : 0.0f;
            mem2x = __fsub_rn(mem2x, __fmul_rn(s2x, TH2));
            mem2y = __fsub_rn(mem2y, __fmul_rn(s2y, TH2));
            const int t = j * SC + s;
            if (tid == 512) {
                s2p[t] = make_float2(s2x, s2y);
                m2p[t] = make_float2(mem2x, mem2y);
            }
            if (t > 0) { accx += (double)mem2x; accy += (double)mem2y; }
        }
    };

    for (int sc = 0; sc < NSC; ++sc) {
        const int t0   = sc * SC;
        const int c    = t0 >> 6;
        const int cpos = t0 & 63;

        if (is_cons) {
            // ---- consumer: this sub-chunk's dots from LDS ----
            float D[SC];
#pragma unroll
            for (int s = 0; s < SC; ++s) D[s] = dotb[sc & 1][s][tid];

            // ---- 8 steps: recurrence + stores + DPP (textually r9's) ----
#pragma unroll
            for (int s = 0; s < SC; ++s) {
                const float dot = D[s];
                syn1 = __fadd_rn(__fmul_rn(A_SYN1, syn1), __fmul_rn(IN_SC1, dot));
                mem1 = __fadd_rn(__fmul_rn(A_MEM1, mem1), __fmul_rn(B_MEM1, syn1));
                const float s1v = (mem1 - TH1 > 0.0f) ? 1.0f : 0.0f;
                mem1 = __fsub_rn(mem1, __fmul_rn(s1v, TH1));

                if (act) {
                    s1p[(size_t)(t0 + s) * HH] = s1v;
                    m1p[(size_t)(t0 + s) * HH] = mem1;
                }

                float cx = s1v * w2x;
                float cy = s1v * w2y;
                wave_sum2(cx, cy);
                if (lane == 63)
                    partv[sc & 1][s][wid] = make_float2(cx, cy);
            }
        } else if (is_prod) {
            // ---- producer: stage x chunks; compute next sub-chunk's dots ----
            if (cpos == 0 && c + 1 < NCH) {
                const int nst = (CH < TT - (c + 1) * CH) ? CH : (TT - (c + 1) * CH);
                nfl4 = nst * DD / 4;
                const float4* g = (const float4*)(xb + (size_t)(c + 1) * CH * DD);
                if (2 * ptid     < nfl4) pr0 = g[2 * ptid];
                if (2 * ptid + 1 < nfl4) pr1 = g[2 * ptid + 1];
            }

            if (sc + 1 < NSC) produce(sc + 1);

            // commit chunk c+1 before producers first read it (at cpos 56)
            if (cpos == 48 && c + 1 < NCH) {
                if (2 * ptid     < nfl4) xls[(c + 1) & 1][2 * ptid]     = pr0;
                if (2 * ptid + 1 < nfl4) xls[(c + 1) & 1][2 * ptid + 1] = pr1;
            }
        } else {
            // ---- wave 8: layer-2 for the previous sub-chunk ----
            if (sc > 0) l2_chunk(sc - 1);
        }

        block_sync_lds();
    }

    // epilogue: layer-2 for the final sub-chunk (wave 8)
    if (wid == 8) {
        l2_chunk(NSC - 1);
        if (tid == 512) {
            outp[b * OO + 0] = (float)accx / 1000.0f;
            outp[b * OO + 1] = (float)accy / 1000.0f;
        }
    }
}

extern "C" void kernel_launch(void* const* d_in, const int* in_sizes, int n_in,
                              void* d_out, int out_size, void* d_ws, size_t ws_size,
                              hipStream_t stream) {
    const float* x  = (const float*)d_in[0];   // [256,1000,32]
    const float* w1 = (const float*)d_in[1];   // [32,200]
    const float* w2 = (const float*)d_in[2];   // [200,2]
    float* out = (float*)d_out;

    dim3 grid(TB), block(576);
    hipLaunchKernelGGL(snn_fwd, grid, block, 0, stream, x, w1, w2, out);
}